// Round 4
// baseline (354.051 us; speedup 1.0000x reference)
//
#include <hip/hip_runtime.h>
#include <stdint.h>

#define BATCH 4
#define N1 25200
#define NROW 50400           // N1 + N2
#define NCLS 100
#define TOT (BATCH*NROW)     // 201600
#define CAP 2048             // max candidates per (batch,class) bucket
#define SCORE_T 0.25f
#define IOU_T 0.45f
#define MAXWH 7680.0f

#define X1_SLAB 64
#define X1_SPB 394           // ceil(25200/64)
#define X2_SLAB 256
#define X2_SPB 99            // ceil(25200/256)

// ---------------- Kernel A: per-row decode via LDS slab staging (coalesced)
__global__ __launch_bounds__(256) void k_rows(const float* __restrict__ x1,
                                              const float* __restrict__ x2,
                                              float* __restrict__ boxes,
                                              float* __restrict__ score,
                                              int* __restrict__ catid,
                                              int* __restrict__ cnt) {
    __shared__ float ld[X2_SLAB * 25];   // 6400 floats = 25.6 KB (>= 64*85)
    int blk = blockIdx.x;
    int t = threadIdx.x;
    const int NX1 = BATCH * X1_SPB;
    if (blk < NX1) {
        int b = blk / X1_SPB, s = blk - b * X1_SPB;
        int r0 = s * X1_SLAB;
        int nr = min(X1_SLAB, N1 - r0);
        const float* src = x1 + ((size_t)b * N1 + r0) * 85;
        int count = nr * 85;
        for (int i = t; i < count; i += 256) ld[i] = src[i];
        __syncthreads();
        int row = t >> 2, sub = t & 3;
        if (row < nr) {
            const float* p = ld + row * 85;
            float conf = p[4];
            // packed key: (score_bits<<32) | ~j  -> max == (score desc, first j)
            unsigned long long key = 0ULL;
            int base = sub * 20;
            for (int c = 0; c < 20; ++c) {
                int j = base + c;
                float v = p[5 + j] * conf;
                unsigned long long kk =
                    ((unsigned long long)__float_as_uint(v) << 32) |
                    (unsigned int)~(unsigned int)j;
                if (kk > key) key = kk;
            }
            unsigned long long o;
            o = __shfl_xor(key, 1, 64); if (o > key) key = o;
            o = __shfl_xor(key, 2, 64); if (o > key) key = o;
            if (sub == 0) {
                float best = __uint_as_float((unsigned int)(key >> 32));
                int bestj = ~(unsigned int)key;
                int r = b * NROW + (r0 + row);
                float cx = p[0], cy = p[1], w = p[2], h = p[3];
                size_t g = (size_t)r * 4;
                boxes[g + 0] = cx - 0.5f * w;
                boxes[g + 1] = cy - 0.5f * h;
                boxes[g + 2] = cx + 0.5f * w;
                boxes[g + 3] = cy + 0.5f * h;
                score[r] = best;
                catid[r] = bestj;
                if (best >= SCORE_T) atomicAdd(&cnt[b * NCLS + bestj], 1);
            }
        }
    } else {
        int blk2 = blk - NX1;
        int b = blk2 / X2_SPB, s = blk2 - b * X2_SPB;
        int r0 = s * X2_SLAB;
        int nr = min(X2_SLAB, N1 - r0);
        const float* src = x2 + ((size_t)b * N1 + r0) * 25;
        int count = nr * 25;
        for (int i = t; i < count; i += 256) ld[i] = src[i];
        __syncthreads();
        if (t < nr) {
            const float* p = ld + t * 25;
            float conf = p[4];
            // classes 0..79 are exact zeros in the padded vector: argmax init (0, j=0)
            float best = 0.0f; int bestj = 0;
            for (int j2 = 0; j2 < 20; ++j2) {
                float v = p[5 + j2] * conf;
                if (v > best) { best = v; bestj = 80 + j2; }
            }
            int r = b * NROW + (N1 + r0 + t);
            float cx = p[0], cy = p[1], w = p[2], h = p[3];
            size_t g = (size_t)r * 4;
            boxes[g + 0] = cx - 0.5f * w;
            boxes[g + 1] = cy - 0.5f * h;
            boxes[g + 2] = cx + 0.5f * w;
            boxes[g + 3] = cy + 0.5f * h;
            score[r] = best;
            catid[r] = bestj;
            if (best >= SCORE_T) atomicAdd(&cnt[b * NCLS + bestj], 1);
        }
    }
}

// ---------------- Kernel B0: exclusive scan of 400 bucket counts
__global__ __launch_bounds__(512) void k_scan(const int* __restrict__ cnt,
                                              int* __restrict__ offs) {
    __shared__ int tmp[512];
    int t = threadIdx.x;
    int v = (t < BATCH * NCLS) ? cnt[t] : 0;
    tmp[t] = v; __syncthreads();
    for (int d = 1; d < 512; d <<= 1) {
        int u = (t >= d) ? tmp[t - d] : 0;
        __syncthreads();
        tmp[t] += u;
        __syncthreads();
    }
    if (t < BATCH * NCLS) offs[t] = tmp[t] - v;   // exclusive
}

// ---------------- Kernel B1: scatter candidate row indices into CSR buckets
__global__ __launch_bounds__(256) void k_scatter(const float* __restrict__ score,
                                                 const int* __restrict__ catid,
                                                 const int* __restrict__ offs,
                                                 int* __restrict__ fill,
                                                 int* __restrict__ csr) {
    int r = blockIdx.x * 256 + threadIdx.x;
    if (r >= TOT) return;
    float s = score[r];
    if (s < SCORE_T) return;
    int b = r / NROW, n = r - b * NROW;
    int bucket = b * NCLS + catid[r];
    int pos = offs[bucket] + atomicAdd(&fill[bucket], 1);
    csr[pos] = n;
}

// ---------------- Kernel C: per-(batch,class) sort + suppression-style NMS
// Serial steps = number of ACCEPTED boxes (<=100), not candidates (~1000).
__global__ __launch_bounds__(256) void k_nms(const float* __restrict__ boxes,
                                             const float* __restrict__ score,
                                             const int* __restrict__ csr,
                                             const int* __restrict__ cntArr,
                                             const int* __restrict__ offs,
                                             unsigned long long* __restrict__ accKey,
                                             int* __restrict__ accCnt) {
    __shared__ unsigned long long sk[CAP];   // 16 KB
    __shared__ float cQ0[CAP];               // SoA quantized boxes, 32 KB total
    __shared__ float cQ1[CAP];
    __shared__ float cQ2[CAP];
    __shared__ float cQ3[CAP];
    __shared__ int red[2][4];
    int bucket = blockIdx.x;
    int b = bucket / NCLS, c = bucket - b * NCLS;
    int cnt0 = cntArr[bucket];
    if (cnt0 > CAP) cnt0 = CAP;
    if (cnt0 == 0) return;            // accCnt zeroed by memset
    int base = offs[bucket];
    int t = threadIdx.x;
    int L = 1; while (L < cnt0) L <<= 1;
    // packed keys: (score_bits << 32) | ~row  -> desc == (score desc, row asc)
    for (int i = t; i < L; i += 256) {
        unsigned long long key = 0ULL;
        if (i < cnt0) {
            int n = csr[base + i];
            unsigned int sb = __float_as_uint(score[b * NROW + n]);
            key = ((unsigned long long)sb << 32) | (unsigned int)(~(unsigned int)n);
        }
        sk[i] = key;
    }
    __syncthreads();
    // bitonic sort, descending
    for (int k = 2; k <= L; k <<= 1) {
        for (int j = k >> 1; j > 0; j >>= 1) {
            for (int i = t; i < L; i += 256) {
                int pp = i ^ j;
                if (pp > i) {
                    bool dir = ((i & k) == 0);
                    unsigned long long a = sk[i], bb = sk[pp];
                    bool sw = dir ? (a < bb) : (a > bb);
                    if (sw) { sk[i] = bb; sk[pp] = a; }
                }
            }
            __syncthreads();
        }
    }
    // stage quantized nms-boxes (box + class*7680, rounded exactly like the ref)
    float off = (float)c * MAXWH;
    for (int i = t; i < cnt0; i += 256) {
        int n = ~(unsigned int)sk[i];
        size_t g = (size_t)(b * NROW + n) * 4;
        cQ0[i] = boxes[g + 0] + off;
        cQ1[i] = boxes[g + 1] + off;
        cQ2[i] = boxes[g + 2] + off;
        cQ3[i] = boxes[g + 3] + off;
    }
    __syncthreads();
    // alive bitmask in registers: thread t owns candidates t, t+256, ...
    int KM = (cnt0 + 255) >> 8;
    unsigned am = 0;
    for (int k = 0; k < KM; ++k)
        if (t + (k << 8) < cnt0) am |= 1u << k;
    int cur = 0, m = 0, parity = 0;
    while (true) {
        if (t == 0) accKey[(size_t)bucket * 100 + m] = sk[cur];
        ++m;
        if (m == 100) break;
        float q0 = cQ0[cur], q1 = cQ1[cur], q2 = cQ2[cur], q3 = cQ3[cur];
        float qa = (q2 - q0) * (q3 - q1);
        int localMin = 0x7fffffff;
        for (int k = 0; k < KM; ++k) {
            if (!((am >> k) & 1)) continue;
            int j = t + (k << 8);
            float a0 = cQ0[j], a1 = cQ1[j], a2 = cQ2[j], a3 = cQ3[j];
            float xx1 = fmaxf(a0, q0), yy1 = fmaxf(a1, q1);
            float xx2 = fminf(a2, q2), yy2 = fminf(a3, q3);
            float inter = fmaxf(xx2 - xx1, 0.0f) * fmaxf(yy2 - yy1, 0.0f);
            float ab = (a2 - a0) * (a3 - a1);
            float iou = inter / (qa + ab - inter + 1e-9f);
            bool na = (j > cur) && !(iou > IOU_T);
            if (!na) am &= ~(1u << k);
            else if (j < localMin) localMin = j;
        }
        int v = localMin;
        for (int o = 1; o < 64; o <<= 1) v = min(v, __shfl_xor(v, o, 64));
        if ((t & 63) == 0) red[parity][t >> 6] = v;
        __syncthreads();
        int next = min(min(red[parity][0], red[parity][1]),
                       min(red[parity][2], red[parity][3]));
        parity ^= 1;
        if (next == 0x7fffffff) break;
        cur = next;
    }
    if (t == 0) accCnt[bucket] = m;
}

// ---------------- Kernel D: per-batch merge, single-wave shuffle tournament
__global__ __launch_bounds__(256) void k_merge(const float* __restrict__ boxes,
                                               const unsigned long long* __restrict__ accKey,
                                               const int* __restrict__ accCnt,
                                               float* __restrict__ out) {
    __shared__ unsigned long long keys[NCLS * 100];   // 80 KB
    __shared__ unsigned long long winKey[100];
    __shared__ int winCls[100];
    __shared__ int cnts[NCLS];
    int b = blockIdx.x;
    int t = threadIdx.x;
    if (t < NCLS) cnts[t] = accCnt[b * NCLS + t];
    __syncthreads();
    // one-shot staging; zero-fill beyond each class's accepted count
    for (int i = t; i < NCLS * 100; i += 256) {
        int c = i / 100, j = i - c * 100;
        keys[i] = (j < cnts[c]) ? accKey[(size_t)(b * NCLS + c) * 100 + j] : 0ULL;
    }
    __syncthreads();
    if (t < 64) {
        int c0 = 2 * t, c1 = 2 * t + 1;     // lanes 50..63 own no real class
        int h0 = 0, h1 = 0;
        unsigned long long hk0 = 0ULL, hk1 = 0ULL;
        if (c0 < NCLS && cnts[c0] > 0) hk0 = keys[c0 * 100];   // OOB guard (crash fix)
        if (c1 < NCLS && cnts[c1] > 0) hk1 = keys[c1 * 100];
        for (int step = 0; step < 100; ++step) {
            unsigned long long k; int cls;
            if (hk0 >= hk1) { k = hk0; cls = c0; } else { k = hk1; cls = c1; }
            for (int o = 1; o < 64; o <<= 1) {
                unsigned long long ok = __shfl_xor(k, o, 64);
                int oc = __shfl_xor(cls, o, 64);
                if (ok > k) { k = ok; cls = oc; }
            }
            if (t == 0) { winKey[step] = k; winCls[step] = cls; }
            if (k != 0ULL) {                // winner is a real class (<NCLS) here
                if (cls == c0)      { ++h0; hk0 = (h0 < cnts[c0]) ? keys[c0 * 100 + h0] : 0ULL; }
                else if (cls == c1) { ++h1; hk1 = (h1 < cnts[c1]) ? keys[c1 * 100 + h1] : 0ULL; }
            }
        }
    }
    __syncthreads();
    if (t < 100) {                          // parallel output gather
        unsigned long long k = winKey[t];
        unsigned int n = ~(unsigned int)k;
        float* o7 = out + (size_t)(b * 100 + t) * 7;
        if (k == 0ULL || n >= (unsigned)NROW) {   // n-clamp: defensive, never true in correct flow
            o7[0] = -1.0f;
            o7[1] = 0.0f; o7[2] = 0.0f; o7[3] = 0.0f;
            o7[4] = 0.0f; o7[5] = 0.0f; o7[6] = 0.0f;
        } else {
            size_t g = (size_t)(b * NROW + (int)n) * 4;
            o7[0] = (float)b;
            o7[1] = boxes[g + 0];
            o7[2] = boxes[g + 1];
            o7[3] = boxes[g + 2];
            o7[4] = boxes[g + 3];
            o7[5] = (float)winCls[t];
            o7[6] = __uint_as_float((unsigned int)(k >> 32));
        }
    }
}

extern "C" void kernel_launch(void* const* d_in, const int* in_sizes, int n_in,
                              void* d_out, int out_size, void* d_ws, size_t ws_size,
                              hipStream_t stream) {
    const float* x1 = (const float*)d_in[0];
    const float* x2 = (const float*)d_in[1];
    float* out = (float*)d_out;

    // workspace layout (~6 MB total)
    float* boxes = (float*)d_ws;                         // TOT*4 f32
    float* score = boxes + (size_t)TOT * 4;              // TOT f32
    int*   catid = (int*)(score + TOT);                  // TOT i32
    int*   csr   = catid + TOT;                          // TOT i32
    unsigned long long* accKey = (unsigned long long*)(csr + TOT);  // 400*100 u64
    int*   cnt    = (int*)(accKey + (size_t)BATCH * NCLS * 100);    // 400
    int*   fill   = cnt + BATCH * NCLS;                  // 400
    int*   accCnt = fill + BATCH * NCLS;                 // 400
    int*   offs   = accCnt + BATCH * NCLS;               // 400

    // zero the three counter arrays (contiguous: cnt, fill, accCnt)
    hipMemsetAsync(cnt, 0, sizeof(int) * 3 * BATCH * NCLS, stream);

    int rowBlocks = BATCH * X1_SPB + BATCH * X2_SPB;     // 1576 + 396
    k_rows<<<rowBlocks, 256, 0, stream>>>(x1, x2, boxes, score, catid, cnt);
    k_scan<<<1, 512, 0, stream>>>(cnt, offs);
    int blocks = (TOT + 255) / 256;
    k_scatter<<<blocks, 256, 0, stream>>>(score, catid, offs, fill, csr);
    k_nms<<<BATCH * NCLS, 256, 0, stream>>>(boxes, score, csr, cnt, offs, accKey, accCnt);
    k_merge<<<BATCH, 256, 0, stream>>>(boxes, accKey, accCnt, out);
}